// Round 9
// baseline (285.879 us; speedup 1.0000x reference)
//
#include <hip/hip_runtime.h>
#include <hip/hip_cooperative_groups.h>
#include <stdint.h>

namespace cg = cooperative_groups;

#define NT 4
#define PP 100
#define TT_BYTES (4ull * 100 * 100 * 1024)     // 40,960,000 B bf16 tT table in d_ws
#define C2B_DWORDS (NT * PP * 64)              // 25600 dwords = 102400 B (exact fit)

// tT layout per combo (tab,i0,i1), 1 KB, row-major [ab=16][s=32] bf16:
//   byte = ab*64 + s*2. MFMA A-frag for lane l is 16B at (l&15)*64 + (l>>4)*16.
// c2b layout per (tab,i2), 256 B, [c=4][s=32] bf16: byte = c*64 + s*2.

typedef short bf16x8 __attribute__((ext_vector_type(8)));
typedef float f32x4  __attribute__((ext_vector_type(4)));

__device__ __forceinline__ uint32_t f2bf(float f) {
    union { float f; uint32_t u; } v; v.f = f;
    uint32_t u = v.u;
    return (u + 0x7fffu + ((u >> 16) & 1u)) >> 16;   // RNE to bf16
}

// ---------------- Fused kernel: {phase1 GEMM + c2pack} -> grid.sync -> phase2 ----------------
// Phase-1 units 0..1599: T[(i0,a)][(b,s)] = c0v @ c1v per (tab, i1, 25-i0 chunk)
//   (identical math/layout to the round-6/8 verified tt_phase1).
// Units 1600..1699: pack c2 as [tab][i2][c=4][s=32] bf16.
// After grid.sync(): bag-major phase2 (identical math to round-3/6/8 control),
//   grid-strided; red[] overlays D_l so LDS stays 40,960 B.
__global__ __launch_bounds__(256)
void tt_fused(const float* __restrict__ c0g, const float* __restrict__ c1g,
              unsigned short* __restrict__ tT,
              const float* __restrict__ c2g, uint32_t* __restrict__ c2p,
              const int* __restrict__ indices, const int* __restrict__ offsets,
              float* __restrict__ out, int bags_per_table, int B) {
    __shared__ uint32_t       A_l[112 * 16];     // [row][kd] kd=k/2, swizzled
    __shared__ uint32_t       B_l[128 * 16];     // [n][rp]  rp=r/2, swizzled
    __shared__ unsigned short D_l[100 * 128];    // [Mrow][n] bf16; reused as red[]

    int tid  = threadIdx.x;
    int lane = tid & 63, wv = tid >> 6;
    int col  = lane & 15, kq = lane >> 4;

    // ================= Phase 1 (grid-stride over 1700 units) =================
    for (int blk = blockIdx.x; blk < 1700; blk += gridDim.x) {
        if (blk >= 1600) {                // ---- c2pack unit ----
            int t = (blk - 1600) * 256 + tid;     // combo*64 + c*16 + sg
            if (t < C2B_DWORDS) {
                int sg = t & 15, c = (t >> 4) & 3, combo = t >> 6;
                const float* src = c2g + (size_t)combo * 128;  // [s=32][c=4] f32
                c2p[t] = f2bf(src[(2 * sg) * 4 + c]) |
                         (f2bf(src[(2 * sg + 1) * 4 + c]) << 16);
            }
        } else {                          // ---- GEMM unit ----
            int tab = blk / 400;
            int rem = blk % 400;
            int i1  = rem >> 2;
            int ch  = rem & 3;            // i0 = ch*25 + i0l, i0l 0..24

            // zero A pad rows 100..111 (dwords 1600..1791)
            if (tid < 192) A_l[1600 + tid] = 0u;

            // stage A: 25 i0 x 128 f32 = 1600 float2, contiguous
            const float2* a2 = (const float2*)(c0g + (size_t)tab * 12800 + (size_t)ch * 3200);
            #pragma unroll
            for (int it = 0; it < 7; ++it) {
                int d = tid + it * 256;
                if (d < 1600) {
                    float2 v = a2[d];
                    int row = d >> 4, kd = d & 15;
                    A_l[row * 16 + (kd ^ ((row & 3) << 2))] = f2bf(v.x) | (f2bf(v.y) << 16);
                }
            }
            // stage B (transpose): c1 row 4096 f32 -> [n][rp] packed pairs
            const float* c1row = c1g + ((size_t)tab * PP + i1) * 4096;
            #pragma unroll
            for (int it = 0; it < 8; ++it) {
                int j = tid + it * 256;   // j < 2048: n = j&127, rp = j>>7
                int n = j & 127, rp = j >> 7;
                float e = c1row[(2 * rp) * 128 + n];
                float o = c1row[(2 * rp + 1) * 128 + n];
                B_l[n * 16 + (rp ^ ((n & 3) << 2))] = f2bf(e) | (f2bf(o) << 16);
            }
            __syncthreads();

            #pragma unroll
            for (int mt = 0; mt < 7; ++mt) {
                #pragma unroll
                for (int ntl = 0; ntl < 2; ++ntl) {
                    int nt = wv * 2 + ntl;
                    int arow = mt * 16 + col;
                    int bn   = nt * 16 + col;
                    bf16x8 af = *(const bf16x8*)&A_l[arow * 16 + ((kq ^ (arow & 3)) << 2)];
                    bf16x8 bf = *(const bf16x8*)&B_l[bn   * 16 + ((kq ^ (bn   & 3)) << 2)];
                    f32x4 acc = {0.f, 0.f, 0.f, 0.f};
                    acc = __builtin_amdgcn_mfma_f32_16x16x32_bf16(af, bf, acc, 0, 0, 0);
                    #pragma unroll
                    for (int q = 0; q < 4; ++q) {
                        int Drow = mt * 16 + kq * 4 + q;   // D row depends only on A row
                        if (Drow < 100)
                            D_l[Drow * 128 + nt * 16 + col] = (unsigned short)f2bf(acc[q]);
                    }
                }
            }
            __syncthreads();

            // copyout: 1600 16B chunks; 16B-contiguous in both D_l and tT
            #pragma unroll
            for (int it = 0; it < 7; ++it) {
                int c = tid + it * 256;
                if (c < 1600) {
                    int Drow = c >> 4, w = c & 15;
                    int i0l = Drow >> 2, a = Drow & 3;
                    int b = w >> 2, so = w & 3;
                    int i0 = ch * 25 + i0l;
                    size_t combo = (size_t)tab * 10000 + (size_t)i0 * 100 + (size_t)i1;
                    char* dst = (char*)tT + combo * 1024 + (size_t)(a * 4 + b) * 64 + (size_t)so * 16;
                    *(uint4*)dst = *(const uint4*)&D_l[Drow * 128 + w * 8];
                }
            }
        }
        __syncthreads();                  // inter-unit LDS reuse fence
    }

    // ============ all tT/c2p writes visible to all blocks ============
    cg::this_grid().sync();

    // ================= Phase 2 (grid-stride over bags) =================
    float* red = (float*)D_l;             // [4][64] overlay, 1 KB
    int aoff = col * 64 + kq * 16;        // A fragment byte offset (row=col)
    int boff = (col & 3) * 64 + kq * 16;  // B fragment byte offset (n=col&3)
    const char* tTb = (const char*)tT;
    const char* c2b = (const char*)c2p;

    for (int bag = blockIdx.x; bag < B; bag += gridDim.x) {
        int tab = bag / bags_per_table;
        int start = offsets[bag];

        uint32_t idx = (uint32_t)indices[start + wv * 4 + (col & 3)];
        uint32_t i0 = idx / 10000u;
        uint32_t r1 = idx - i0 * 10000u;
        uint32_t i1 = r1 / 100u;
        uint32_t i2 = r1 - i1 * 100u;
        uint32_t tby = (((uint32_t)tab * 10000u + i0 * 100u + i1) << 10);  // *1024
        uint32_t cby = (((uint32_t)tab * 100u + i2) << 8);                 // *256

        bf16x8 A[4], Bv[4];
        #pragma unroll
        for (int jj = 0; jj < 4; ++jj) {
            uint32_t tb = (uint32_t)__builtin_amdgcn_readlane((int)tby, jj);
            uint32_t cb = (uint32_t)__builtin_amdgcn_readlane((int)cby, jj);
            A[jj]  = *(const bf16x8*)(tTb + tb + aoff);
            Bv[jj] = *(const bf16x8*)(c2b + cb + boff);
        }

        f32x4 acc = {0.f, 0.f, 0.f, 0.f};
        #pragma unroll
        for (int jj = 0; jj < 4; ++jj)
            acc = __builtin_amdgcn_mfma_f32_16x16x32_bf16(A[jj], Bv[jj], acc, 0, 0, 0);

        if (col < 4) {
            #pragma unroll
            for (int q = 0; q < 4; ++q)
                red[wv * 64 + kq * 16 + q * 4 + col] = acc[q];
        }
        __syncthreads();
        if (wv == 0) {
            float s = red[lane] + red[64 + lane] + red[128 + lane] + red[192 + lane];
            out[(size_t)bag * 64 + lane] = s;
        }
        __syncthreads();                  // protect red[] before next bag
    }
}

extern "C" void kernel_launch(void* const* d_in, const int* in_sizes, int n_in,
                              void* d_out, int out_size, void* d_ws, size_t ws_size,
                              hipStream_t stream) {
    const int*   indices = (const int*)d_in[0];
    const int*   offsets = (const int*)d_in[1];
    const float* c0      = (const float*)d_in[2];
    const float* c1      = (const float*)d_in[3];
    const float* c2      = (const float*)d_in[4];
    float* out = (float*)d_out;

    int B = in_sizes[1] - 1;              // 32768 bags
    int bags_per_table = B / NT;          // 8192

    unsigned short* tT  = (unsigned short*)d_ws;
    uint32_t*       c2p = (uint32_t*)((char*)d_ws + TT_BYTES);

    // Cooperative grid: exactly the co-resident capacity (MI355X: 256 CUs).
    static int maxb = -1;
    if (maxb < 0) {
        (void)hipOccupancyMaxActiveBlocksPerMultiprocessor(&maxb, tt_fused, 256, 0);
        if (maxb < 1) maxb = 1;
    }
    int grid = maxb * 256;
    if (grid > B) grid = B;

    void* args[] = { (void*)&c0, (void*)&c1, (void*)&tT, (void*)&c2, (void*)&c2p,
                     (void*)&indices, (void*)&offsets, (void*)&out,
                     (void*)&bags_per_table, (void*)&B };
    (void)hipLaunchCooperativeKernel((void*)tt_fused, dim3(grid), dim3(256),
                                     args, 0, stream);
}

// Round 11
// 144.922 us; speedup vs baseline: 1.9726x; 1.9726x over previous
//
#include <hip/hip_runtime.h>
#include <stdint.h>

#define NT 4
#define PP 100
#define TT_BYTES (4ull * 100 * 100 * 1024)     // 40,960,000 B bf16 tT table in d_ws
#define C2B_DWORDS (NT * PP * 64)              // 25600 dwords = 102400 B (exact fit)

// tT layout per combo (tab,i0,i1), 1 KB, row-major [ab=16][s=32] bf16:
//   byte = ab*64 + s*2. MFMA A-frag for lane l is 16B at (l&15)*64 + (l>>4)*16.
// c2b layout per (tab,i2), 256 B, [c=4][s=32] bf16: byte = c*64 + s*2.

typedef short bf16x8 __attribute__((ext_vector_type(8)));
typedef float f32x4  __attribute__((ext_vector_type(4)));

__device__ __forceinline__ uint32_t f2bf(float f) {
    union { float f; uint32_t u; } v; v.f = f;
    uint32_t u = v.u;
    return (u + 0x7fffu + ((u >> 16) & 1u)) >> 16;   // RNE to bf16
}

// ---------------- Phase 1 (MFMA) + merged c2pack (byte-identical to round 6/8) ----------------
__global__ __launch_bounds__(256)
void tt_phase1(const float* __restrict__ c0g, const float* __restrict__ c1g,
               unsigned short* __restrict__ tT,
               const float* __restrict__ c2g, uint32_t* __restrict__ c2p) {
    __shared__ uint32_t       A_l[112 * 16];     // [row][kd] kd=k/2, swizzled
    __shared__ uint32_t       B_l[128 * 16];     // [n][rp]  rp=r/2, swizzled
    __shared__ unsigned short D_l[100 * 128];    // [Mrow][n] bf16

    int blk = blockIdx.x;                 // 1600 GEMM blocks + 100 pack blocks
    int tid = threadIdx.x;

    if (blk >= 1600) {                    // ---- c2pack path (whole block) ----
        int t = (blk - 1600) * 256 + tid; // combo*64 + c*16 + sg
        if (t < C2B_DWORDS) {
            int sg = t & 15, c = (t >> 4) & 3, combo = t >> 6;
            const float* src = c2g + (size_t)combo * 128;  // [s=32][c=4] f32
            c2p[t] = f2bf(src[(2 * sg) * 4 + c]) | (f2bf(src[(2 * sg + 1) * 4 + c]) << 16);
        }
        return;
    }

    int tab = blk / 400;
    int rem = blk % 400;
    int i1  = rem >> 2;
    int ch  = rem & 3;                    // i0 = ch*25 + i0l, i0l 0..24

    // --- zero A pad rows 100..111 (dwords 1600..1791) ---
    if (tid < 192) A_l[1600 + tid] = 0u;

    // --- stage A: 25 i0 x 128 f32 = 1600 float2, contiguous ---
    const float2* a2 = (const float2*)(c0g + (size_t)tab * 12800 + (size_t)ch * 3200);
    #pragma unroll
    for (int it = 0; it < 7; ++it) {
        int d = tid + it * 256;
        if (d < 1600) {
            float2 v = a2[d];
            int row = d >> 4, kd = d & 15;
            A_l[row * 16 + (kd ^ ((row & 3) << 2))] = f2bf(v.x) | (f2bf(v.y) << 16);
        }
    }
    // --- stage B (transpose): c1 row 4096 f32 -> [n][rp] packed pairs ---
    const float* c1row = c1g + ((size_t)tab * PP + i1) * 4096;
    #pragma unroll
    for (int it = 0; it < 8; ++it) {
        int j = tid + it * 256;           // j < 2048: n = j&127, rp = j>>7
        int n = j & 127, rp = j >> 7;
        float e = c1row[(2 * rp) * 128 + n];
        float o = c1row[(2 * rp + 1) * 128 + n];
        B_l[n * 16 + (rp ^ ((n & 3) << 2))] = f2bf(e) | (f2bf(o) << 16);
    }
    __syncthreads();

    int lane = tid & 63, wv = tid >> 6;
    int col = lane & 15, kq = lane >> 4;

    #pragma unroll
    for (int mt = 0; mt < 7; ++mt) {
        #pragma unroll
        for (int ntl = 0; ntl < 2; ++ntl) {
            int nt = wv * 2 + ntl;
            int arow = mt * 16 + col;
            int bn   = nt * 16 + col;
            bf16x8 af = *(const bf16x8*)&A_l[arow * 16 + ((kq ^ (arow & 3)) << 2)];
            bf16x8 bf = *(const bf16x8*)&B_l[bn   * 16 + ((kq ^ (bn   & 3)) << 2)];
            f32x4 acc = {0.f, 0.f, 0.f, 0.f};
            acc = __builtin_amdgcn_mfma_f32_16x16x32_bf16(af, bf, acc, 0, 0, 0);
            #pragma unroll
            for (int q = 0; q < 4; ++q) {
                int Drow = mt * 16 + kq * 4 + q;     // D row depends only on A row
                if (Drow < 100)
                    D_l[Drow * 128 + nt * 16 + col] = (unsigned short)f2bf(acc[q]);
            }
        }
    }
    __syncthreads();

    // --- copyout: 1600 16B chunks; 16B-contiguous in both D_l and tT ---
    #pragma unroll
    for (int it = 0; it < 7; ++it) {
        int c = tid + it * 256;
        if (c < 1600) {
            int Drow = c >> 4, w = c & 15;
            int i0l = Drow >> 2, a = Drow & 3;
            int b = w >> 2, so = w & 3;
            int i0 = ch * 25 + i0l;
            size_t combo = (size_t)tab * 10000 + (size_t)i0 * 100 + (size_t)i1;
            char* dst = (char*)tT + combo * 1024 + (size_t)(a * 4 + b) * 64 + (size_t)so * 16;
            *(uint4*)dst = *(const uint4*)&D_l[Drow * 128 + w * 8];
        }
    }
}

// ---------------- Phase 2: bag per BLOCK, 4 waves x 4 lookups, sched_barrier-forced ILP ----------------
// Rounds 2/3/6/8 all compiled to a rolled load->wait->MFMA schedule (VGPR=20,
// ~1-2 loads in flight/wave). __builtin_amdgcn_sched_barrier(0) between the
// load loop and the MFMA chain forbids any instruction from crossing, so all
// 8 global_load_dwordx4 issue before the first MFMA (8 in flight per wave).
__global__ __launch_bounds__(256, 6)
void tt_phase2(const int* __restrict__ indices, const int* __restrict__ offsets,
               const char* __restrict__ tT, const char* __restrict__ c2b,
               float* __restrict__ out, int bags_per_table, int B) {
    __shared__ float red[4][64];
    int lane = threadIdx.x & 63;
    int wv   = threadIdx.x >> 6;         // 0..3: this wave's 4 lookups
    int bag  = blockIdx.x;
    int col = lane & 15;
    int kq  = lane >> 4;
    int tab = bag / bags_per_table;
    int start = offsets[bag];

    uint32_t idx = (uint32_t)indices[start + wv * 4 + (col & 3)];
    uint32_t i0 = idx / 10000u;
    uint32_t r1 = idx - i0 * 10000u;
    uint32_t i1 = r1 / 100u;
    uint32_t i2 = r1 - i1 * 100u;
    uint32_t tby = (((uint32_t)tab * 10000u + i0 * 100u + i1) << 10);  // *1024
    uint32_t cby = (((uint32_t)tab * 100u + i2) << 8);                 // *256

    int aoff = col * 64 + kq * 16;        // A fragment byte offset (row=col)
    int boff = (col & 3) * 64 + kq * 16;  // B fragment byte offset (n=col&3)

    bf16x8 A[4], Bv[4];
    #pragma unroll
    for (int jj = 0; jj < 4; ++jj) {
        uint32_t tb = (uint32_t)__builtin_amdgcn_readlane((int)tby, jj);
        uint32_t cb = (uint32_t)__builtin_amdgcn_readlane((int)cby, jj);
        A[jj]  = *(const bf16x8*)(tT  + tb + aoff);
        Bv[jj] = *(const bf16x8*)(c2b + cb + boff);
    }
    // No instruction may cross: all 8 loads issue before any MFMA.
    __builtin_amdgcn_sched_barrier(0);

    f32x4 acc = {0.f, 0.f, 0.f, 0.f};
    #pragma unroll
    for (int jj = 0; jj < 4; ++jj)
        acc = __builtin_amdgcn_mfma_f32_16x16x32_bf16(A[jj], Bv[jj], acc, 0, 0, 0);

    if (col < 4) {
        #pragma unroll
        for (int q = 0; q < 4; ++q)
            red[wv][kq * 16 + q * 4 + col] = acc[q];
    }
    __syncthreads();
    if (wv == 0) {
        float s = red[0][lane] + red[1][lane] + red[2][lane] + red[3][lane];
        out[(size_t)bag * 64 + lane] = s;
    }
}

extern "C" void kernel_launch(void* const* d_in, const int* in_sizes, int n_in,
                              void* d_out, int out_size, void* d_ws, size_t ws_size,
                              hipStream_t stream) {
    const int*   indices = (const int*)d_in[0];
    const int*   offsets = (const int*)d_in[1];
    const float* c0      = (const float*)d_in[2];
    const float* c1      = (const float*)d_in[3];
    const float* c2      = (const float*)d_in[4];
    float* out = (float*)d_out;

    int B = in_sizes[1] - 1;              // 32768 bags
    int bags_per_table = B / NT;          // 8192

    unsigned short* tT  = (unsigned short*)d_ws;
    uint32_t*       c2p = (uint32_t*)((char*)d_ws + TT_BYTES);

    tt_phase1<<<dim3(1700), dim3(256), 0, stream>>>(c0, c1, tT, c2, c2p);
    tt_phase2<<<dim3(B), dim3(256), 0, stream>>>(indices, offsets,
                                                 (const char*)tT,
                                                 (const char*)c2p, out,
                                                 bags_per_table, B);
}